// Round 11
// baseline (780.693 us; speedup 1.0000x reference)
//
#include <hip/hip_runtime.h>

#define H 512
#define NBLK 4096
#define STEPC (2.4f / 63.0f)

typedef _Float16 half8 __attribute__((ext_vector_type(8)));
typedef _Float16 half4_t __attribute__((ext_vector_type(4)));
typedef float floatx16 __attribute__((ext_vector_type(16)));
typedef float floatx4 __attribute__((ext_vector_type(4)));

// fast silu: native exp + fast div. rel-err ~1e-7, negligible vs fp16 rounding.
__device__ inline float silu_f(float x) {
    return __fdividef(x, 1.0f + __expf(-x));
}

// ---- fused prep: blocks 0..1023 -> W image; blocks 1024..1025 -> latw ----
// W image layout: [l][wv][hi][ks][nt][lm][e]  (halves)
//   idx = (l*8+wv)*32768 + hi*16384 + ks*512 + nt*256 + lm*8 + e
__global__ void prep_fused(const float* __restrict__ lat, const float* __restrict__ W0,
                           const float* __restrict__ b0,
                           const float* __restrict__ W1, const float* __restrict__ W2,
                           float* __restrict__ latw, _Float16* __restrict__ ws) {
    __shared__ float sl[H];
    if (blockIdx.x < 1024) {
        const int id = blockIdx.x * 512 + threadIdx.x;   // 0 .. 524287
        const int l = id >> 18;
        const int rem = id & 0x3FFFF;                    // k*512 + n
        const int k = rem >> 9, n = rem & 511;
        const float w = (l == 0 ? W1 : W2)[rem];
        const int ks = k >> 4, hi = (k >> 3) & 1, e = k & 7;
        const int wv = n >> 6, nt = (n >> 5) & 1, lm = n & 31;
        ws[(size_t)(l * 8 + wv) * 32768 + hi * 16384 + ks * 512 + nt * 256 + lm * 8 + e]
            = (_Float16)w;
    } else {
        const int b = blockIdx.x - 1024;
        const int j = threadIdx.x;
        sl[j] = lat[b * H + j];
        __syncthreads();
        float acc = b0[j];
#pragma unroll 8
        for (int d = 0; d < H; ++d) acc += sl[d] * W0[d * H + j];
        latw[b * H + j] = acc;
    }
}

// ---- main fused kernel ----
// R11: HALVE THE L2-W TERM. Serialized-sum model (R10 post-mortem):
// per CU block-pair = MFMA 33K + L2-W 35K + LDS-A 25K + VALU 12K = 105K
// ~ measured 110K; all variants left the terms unchanged -> identical dur.
// The L2-W term is 2x the algorithmic minimum: both resident blocks read
// the full 1MB W image for only 64 rows each. Fix: MTILE=128, 8 fat waves,
// wave tile 128m x 64n (acc 4x2 blocks = 128 AGPR), 1 block/CU at
// launch_bounds(512,2) (256-reg budget). Each W byte feeds 128 rows ->
// L2 term 17.5K. LDS/MFMA terms unchanged; phase VALU doubles (~+3K).
// Keeps R10: drain-free lgkm-only barriers, asm W queue + counted vmcnt
// (never 0 mid-loop), cross-barrier prefetch, setprio on MFMA cluster.
// LDS: h 128KB + lwq 8KB + partials 4KB = 140KB (<=160, R3 proved >64KB ok).
__global__ __launch_bounds__(512, 2) void mesh_main(
    const float* __restrict__ W0, const float* __restrict__ b1,
    const float* __restrict__ b2, const float* __restrict__ W3,
    const float* __restrict__ b3, const float* __restrict__ latw,
    const _Float16* __restrict__ wsB, float* __restrict__ out) {

    __shared__ _Float16 hbuf2[8192 * 8];          // 128 KB: [64 reg g][128 row][8]
    __shared__ floatx4 lwq[H];                    // 8 KB: (lw, w1c, w2c, -)
    __shared__ float partials[8][128];            // 4 KB -> 140 KB total

    const int tid = threadIdx.x;
    const int wave = tid >> 6, lane = tid & 63;
    const int lm = lane & 31, hi = lane >> 5;
    const int uwave = __builtin_amdgcn_readfirstlane(wave);  // force SGPR
    const int bi = blockIdx.x;
    const int b = bi >> 11;                       // 2 latents x 2048 tiles
    const int pi = bi & 2047;                     // tile: x = pi>>5, y0 = (pi&31)*2
    const float c0 = -1.2f + (float)(pi >> 5) * STEPC;
    const float c1 = -1.2f + (float)((pi & 31) << 1) * STEPC;

    // drain-free phase barrier: orders LDS only; vmcnt queue stays in flight
    auto phase_barrier = [&]() {
        __builtin_amdgcn_sched_barrier(0);
        asm volatile("s_waitcnt lgkmcnt(0)" ::: "memory");
        __builtin_amdgcn_s_barrier();
        __builtin_amdgcn_sched_barrier(0);
    };

    // per-lane bases
    const int vWoffB = hi * 32768 + lm * 16;             // W: loop-constant byte voffset
    const _Float16* hb = hbuf2 + hi * 1024 + lm * 8;     // A: LDS base

    floatx16 acc[4][2];                            // [mb][nt]: 128 AGPR

    auto zero_acc = [&]() {
#pragma unroll
        for (int mb = 0; mb < 4; ++mb)
#pragma unroll
            for (int nt = 0; nt < 2; ++nt)
#pragma unroll
                for (int r = 0; r < 16; ++r) acc[mb][nt][r] = 0.f;
    };

    // asm-pinned W-fragment load pair: saddr uniform, voffset constant, imm nt
    auto issueW = [&](const _Float16* base, int ks, half8 (&wf)[2]) {
        const _Float16* sp = base + ks * 512;            // uniform (SALU add)
        asm volatile("global_load_dwordx4 %0, %2, %3\n\t"
                     "global_load_dwordx4 %1, %2, %3 offset:512"
                     : "=v"(wf[0]), "=v"(wf[1])
                     : "v"(vWoffB), "s"(sp)
                     : "memory");
    };

    auto loadA = [&](int ks, half8 (&a)[4]) {
        const _Float16* hp = hb + ks * 2048;
#pragma unroll
        for (int mb = 0; mb < 4; ++mb)
            a[mb] = *(const half8*)(hp + mb * 256);      // conflict-free b128
    };

    auto compute = [&](half8 (&wf)[2], half8 (&a)[4]) {
        __builtin_amdgcn_s_setprio(1);
#pragma unroll
        for (int nt = 0; nt < 2; ++nt)
#pragma unroll
            for (int mb = 0; mb < 4; ++mb)
                acc[mb][nt] = __builtin_amdgcn_mfma_f32_32x32x16_f16(wf[nt], a[mb], acc[mb][nt], 0, 0, 0);
        __builtin_amdgcn_s_setprio(0);
    };

    const _Float16* wbase0 = wsB + (size_t)uwave * 32768;         // GEMM1 (W1)
    const _Float16* wbase1 = wsB + (size_t)(8 + uwave) * 32768;   // GEMM2 (W2)

    half8 Wq[3][2];        // W queue, shared across both GEMMs

    // K-loop body: assumes chunks 0..2 already in flight (issued pre-barrier).
    auto run_gemm_body = [&](const _Float16* base) {
        half8 Aq[2][4];
        loadA(0, Aq[0]);
        loadA(1, Aq[1]);
#pragma unroll
        for (int ks = 0; ks < 32; ++ks) {       // fully unrolled, static indices
            if (ks <= 29)      asm volatile("s_waitcnt vmcnt(4)" ::: "memory");
            else if (ks == 30) asm volatile("s_waitcnt vmcnt(2)" ::: "memory");
            else               asm volatile("s_waitcnt vmcnt(0)" ::: "memory");
            __builtin_amdgcn_sched_barrier(0);
            compute(Wq[ks % 3], Aq[ks % 2]);
            if (ks + 3 < 32) issueW(base, ks + 3, Wq[ks % 3]);   // slot just consumed
            if (ks + 2 < 32) loadA(ks + 2, Aq[ks % 2]);          // compiler-ordered
        }
    };

    // ---- layer 0, phase A: lw = latw + c0*W0x; keep (W0y, W0z) per col ----
    {
        const int j = tid;
        floatx4 v;
        v[0] = latw[b * H + j] + c0 * W0[(H + 0) * H + j];
        v[1] = W0[(H + 1) * H + j];
        v[2] = W0[(H + 2) * H + j];
        v[3] = 0.f;
        lwq[j] = v;
    }
    phase_barrier();

    // ---- layer 0, phase B: wave owns regions g = wave*8+s; rows in 2 halves
    // row = half*64 + lane: y = y0+half, z = lane. Whole-wave 1KB writes. ----
    {
        const float cz = -1.2f + (float)lane * STEPC;
#pragma unroll
        for (int s = 0; s < 8; ++s) {
            const int g = wave * 8 + s;
            floatx4 pv[8];
#pragma unroll
            for (int i = 0; i < 8; ++i) pv[i] = lwq[g * 8 + i];  // broadcast
#pragma unroll
            for (int half = 0; half < 2; ++half) {
                const float cy = c1 + (float)half * STEPC;
                half8 hv;
#pragma unroll
                for (int i = 0; i < 8; ++i)
                    hv[i] = (_Float16)silu_f(pv[i][0] + cy * pv[i][1] + cz * pv[i][2]);
                *(half8*)&hbuf2[(g * 128 + half * 64 + lane) * 8] = hv;
            }
        }
    }
    zero_acc();
    __builtin_amdgcn_sched_barrier(0);
    issueW(wbase0, 0, Wq[0]);         // G1 prefetch: survives the barrier
    issueW(wbase0, 1, Wq[1]);
    issueW(wbase0, 2, Wq[2]);
    phase_barrier();                  // h0 ready

    // ---- GEMM 1 ----
    run_gemm_body(wbase0);
    phase_barrier();                  // all waves done reading h0

    // writeback h1 = silu(acc + b1): lane owns, per (mb,nt,g4), 4 consecutive
    // n = wave*64 + nt*32 + g4*8 + hi*4 .. +3 at row m = mb*32 + lm
    {
        floatx4 b1v[2][4];
#pragma unroll
        for (int nt = 0; nt < 2; ++nt)
#pragma unroll
            for (int g4 = 0; g4 < 4; ++g4)
                b1v[nt][g4] = *(const floatx4*)&b1[wave * 64 + nt * 32 + g4 * 8 + hi * 4];
#pragma unroll
        for (int mb = 0; mb < 4; ++mb)
#pragma unroll
            for (int nt = 0; nt < 2; ++nt)
#pragma unroll
                for (int g4 = 0; g4 < 4; ++g4) {
                    half4_t hv;
#pragma unroll
                    for (int j = 0; j < 4; ++j)
                        hv[j] = (_Float16)silu_f(acc[mb][nt][g4 * 4 + j] + b1v[nt][g4][j]);
                    const int gg = wave * 8 + nt * 4 + g4;
                    *(half4_t*)&hbuf2[(gg * 128 + mb * 32 + lm) * 8 + hi * 4] = hv;
                }
    }
    zero_acc();
    __builtin_amdgcn_sched_barrier(0);
    issueW(wbase1, 0, Wq[0]);         // G2 prefetch: survives the barrier
    issueW(wbase1, 1, Wq[1]);
    issueW(wbase1, 2, Wq[2]);
    phase_barrier();                  // h1 ready

    // ---- GEMM 2 ----
    run_gemm_body(wbase1);

    // ---- final layer: out = silu(acc + b2) @ W3 + b3, fp32 VALU ----
    {
        floatx4 b2v[2][4], w3v[2][4];
#pragma unroll
        for (int nt = 0; nt < 2; ++nt)
#pragma unroll
            for (int g4 = 0; g4 < 4; ++g4) {
                const int n0 = wave * 64 + nt * 32 + g4 * 8 + hi * 4;
                b2v[nt][g4] = *(const floatx4*)&b2[n0];
                w3v[nt][g4] = *(const floatx4*)&W3[n0];
            }
#pragma unroll
        for (int mb = 0; mb < 4; ++mb) {
            float sum = 0.f;
#pragma unroll
            for (int nt = 0; nt < 2; ++nt)
#pragma unroll
                for (int g4 = 0; g4 < 4; ++g4)
#pragma unroll
                    for (int j = 0; j < 4; ++j)
                        sum += silu_f(acc[mb][nt][g4 * 4 + j] + b2v[nt][g4][j]) * w3v[nt][g4][j];
            sum += __shfl_xor(sum, 32);        // combine hi halves (same m)
            if (hi == 0) partials[wave][mb * 32 + lm] = sum;
        }
    }
    phase_barrier();
    if (tid < 128) {
        float o = b3[0];
#pragma unroll
        for (int w = 0; w < 8; ++w) o += partials[w][tid];
        out[(size_t)bi * 128 + tid] = o;
    }
}

extern "C" void kernel_launch(void* const* d_in, const int* in_sizes, int n_in,
                              void* d_out, int out_size, void* d_ws, size_t ws_size,
                              hipStream_t stream) {
    const float* lat = (const float*)d_in[0];
    const float* W0  = (const float*)d_in[1];
    const float* b0  = (const float*)d_in[2];
    const float* W1  = (const float*)d_in[3];
    const float* b1  = (const float*)d_in[4];
    const float* W2  = (const float*)d_in[5];
    const float* b2  = (const float*)d_in[6];
    const float* W3  = (const float*)d_in[7];
    const float* b3  = (const float*)d_in[8];
    float* out = (float*)d_out;

    float* latw = (float*)d_ws;                               // 4 KB
    _Float16* wsB = (_Float16*)((char*)d_ws + 4096);          // 1 MB

    prep_fused<<<1026, 512, 0, stream>>>(lat, W0, b0, W1, W2, latw, wsB);
    mesh_main<<<NBLK, 512, 0, stream>>>(W0, b1, b2, W3, b3, latw, wsB, out);
}